// Round 1
// baseline (213.725 us; speedup 1.0000x reference)
//
#include <hip/hip_runtime.h>
#include <hip/hip_bf16.h>
#include <cstdint>

#define KDIM 512
#define BM 128
#define BN 128
#define BK 64
#define M_MAIN 100352   // 512*196
#define NPIX 196
#define BATCH 512

typedef float f32x4 __attribute__((ext_vector_type(4)));
typedef short s16x8 __attribute__((ext_vector_type(8)));
typedef short s16x4 __attribute__((ext_vector_type(4)));

__device__ __forceinline__ short f2bf(float f) {
    uint32_t u = __float_as_uint(f);
    uint32_t r = u + 0x7FFFu + ((u >> 16) & 1u);   // round-to-nearest-even
    return (short)(r >> 16);
}

__device__ __forceinline__ void gload_lds16(const void* g, void* l) {
    __builtin_amdgcn_global_load_lds(
        (const __attribute__((address_space(1))) void*)g,
        (__attribute__((address_space(3))) void*)l, 16, 0, 0);
}

// Transpose + convert W [K][A] fp32 -> Wt [A][K] bf16 for both weight matrices.
__global__ void prep_w(const float* __restrict__ W_enc, const float* __restrict__ W_dec,
                       short* __restrict__ Wt_enc, short* __restrict__ Wt_dec) {
    int a = blockIdx.x;
    int k = threadIdx.x;
    const float* W = blockIdx.y ? W_dec : W_enc;
    short* Wt = blockIdx.y ? Wt_dec : Wt_enc;
    Wt[a * KDIM + k] = f2bf(W[(size_t)k * KDIM + a]);
}

// EPI==0: write out[row][col] = acc + b1[col] + b2[col]   (att_dec' precompute)
// EPI==1: energy partials: out[(blockIdx.x*2+wn)*M + row] =
//           sum_cols relu(acc + attdec[row/196][col]) * wfull[col]
template <int EPI>
__launch_bounds__(256, 2)
__global__ void gemm_fused(const float* __restrict__ A, int M,
                           const short* __restrict__ Bt,
                           const float* __restrict__ b1, const float* __restrict__ b2,
                           const float* __restrict__ attdec, const float* __restrict__ wfull,
                           float* __restrict__ outp) {
    __shared__ short lds_a[2][BM][BK];
    __shared__ short lds_b[2][BN][BK];

    const int tid = threadIdx.x;
    const int wave = tid >> 6;
    const int lane = tid & 63;
    const int wm = wave >> 1;       // 2 waves along M
    const int wn = wave & 1;        // 2 waves along N
    const int r0 = blockIdx.y * BM;
    const int c0 = blockIdx.x * BN;

    f32x4 areg[8];

    auto loadA = [&](int kt) {
#pragma unroll
        for (int j = 0; j < 8; ++j) {
            int f = tid + 256 * j;          // float4 index in 128x64 tile (16 per row)
            int row = f >> 4, c4 = f & 15;
            areg[j] = *(const f32x4*)(A + (size_t)(r0 + row) * KDIM + kt * BK + c4 * 4);
        }
    };
    auto writeA = [&](int buf) {
#pragma unroll
        for (int j = 0; j < 8; ++j) {
            int f = tid + 256 * j;
            int row = f >> 4, c4 = (f & 15) * 4;
            f32x4 v = areg[j];
            s16x4 o;
            o[0] = f2bf(v[0]); o[1] = f2bf(v[1]); o[2] = f2bf(v[2]); o[3] = f2bf(v[3]);
            *(s16x4*)&lds_a[buf][row][c4] = o;
        }
    };
    auto stageB = [&](int buf, int kt) {
#pragma unroll
        for (int i = 0; i < 4; ++i) {
            int rb = wave * 32 + i * 8;     // 8 rows per issue (64 lanes * 16B)
            const short* g = Bt + (size_t)(c0 + rb + (lane >> 3)) * KDIM + kt * BK + (lane & 7) * 8;
            gload_lds16(g, &lds_b[buf][rb][0]);
        }
    };

    f32x4 acc[4][4];
#pragma unroll
    for (int i = 0; i < 4; ++i)
#pragma unroll
        for (int j = 0; j < 4; ++j)
            acc[i][j] = (f32x4){0.f, 0.f, 0.f, 0.f};

    auto compute = [&](int buf) {
#pragma unroll
        for (int kk = 0; kk < 2; ++kk) {
            s16x8 af[4], bf[4];
#pragma unroll
            for (int fm = 0; fm < 4; ++fm)
                af[fm] = *(const s16x8*)&lds_a[buf][wm * 64 + fm * 16 + (lane & 15)][kk * 32 + (lane >> 4) * 8];
#pragma unroll
            for (int fn = 0; fn < 4; ++fn)
                bf[fn] = *(const s16x8*)&lds_b[buf][wn * 64 + fn * 16 + (lane & 15)][kk * 32 + (lane >> 4) * 8];
#pragma unroll
            for (int fm = 0; fm < 4; ++fm)
#pragma unroll
                for (int fn = 0; fn < 4; ++fn)
                    acc[fm][fn] = __builtin_amdgcn_mfma_f32_16x16x32_bf16(af[fm], bf[fn], acc[fm][fn], 0, 0, 0);
        }
    };

    // Prologue: stage tile 0
    loadA(0);
    stageB(0, 0);
    writeA(0);
    __syncthreads();

    const int nk = KDIM / BK;   // 8
    for (int t = 0; t < nk; ++t) {
        int cur = t & 1;
        if (t + 1 < nk) {
            loadA(t + 1);
            stageB(cur ^ 1, t + 1);
        }
        compute(cur);
        if (t + 1 < nk) writeA(cur ^ 1);
        __syncthreads();
    }

    const int lcol = lane & 15;
    const int lrg = (lane >> 4) * 4;

    if constexpr (EPI == 0) {
#pragma unroll
        for (int fm = 0; fm < 4; ++fm)
#pragma unroll
            for (int fn = 0; fn < 4; ++fn) {
                int col = c0 + wn * 64 + fn * 16 + lcol;
                float bias = b1[col] + b2[col];
#pragma unroll
                for (int reg = 0; reg < 4; ++reg) {
                    int row = r0 + wm * 64 + fm * 16 + lrg + reg;
                    outp[(size_t)row * KDIM + col] = acc[fm][fn][reg] + bias;
                }
            }
    } else {
        float wfv[4];
        int colv[4];
#pragma unroll
        for (int fn = 0; fn < 4; ++fn) {
            colv[fn] = c0 + wn * 64 + fn * 16 + lcol;
            wfv[fn] = wfull[colv[fn]];
        }
        const int slice = blockIdx.x * 2 + wn;
#pragma unroll
        for (int fm = 0; fm < 4; ++fm) {
#pragma unroll
            for (int reg = 0; reg < 4; ++reg) {
                int row = r0 + wm * 64 + fm * 16 + lrg + reg;
                int b = row / NPIX;
                float es = 0.f;
#pragma unroll
                for (int fn = 0; fn < 4; ++fn) {
                    float v = acc[fm][fn][reg] + attdec[(size_t)b * KDIM + colv[fn]];
                    v = fmaxf(v, 0.f);
                    es = fmaf(v, wfv[fn], es);
                }
#pragma unroll
                for (int m = 1; m < 16; m <<= 1) es += __shfl_xor(es, m);
                if (lcol == 0) outp[(size_t)slice * M + row] = es;
            }
        }
    }
}

// One block per batch element: sum 8 energy partials, softmax over 196, write alpha,
// then context[b][e] = sum_p enc[b][p][e] * alpha[p].
__global__ void softmax_ctx(const float* __restrict__ enc, const float* __restrict__ energy8,
                            float* __restrict__ out) {
    const int b = blockIdx.x;
    const int t = threadIdx.x;  // 256
    __shared__ float sal[NPIX];
    __shared__ float wred[4];

    float e = -1e30f;
    if (t < NPIX) {
        float s = 0.f;
#pragma unroll
        for (int i = 0; i < 8; ++i) s += energy8[(size_t)i * M_MAIN + b * NPIX + t];
        e = s;
    }
    float m = e;
#pragma unroll
    for (int d = 1; d < 64; d <<= 1) m = fmaxf(m, __shfl_xor(m, d));
    if ((t & 63) == 0) wred[t >> 6] = m;
    __syncthreads();
    m = fmaxf(fmaxf(wred[0], wred[1]), fmaxf(wred[2], wred[3]));

    float ex = (t < NPIX) ? __expf(e - m) : 0.f;
    float sm = ex;
#pragma unroll
    for (int d = 1; d < 64; d <<= 1) sm += __shfl_xor(sm, d);
    __syncthreads();
    if ((t & 63) == 0) wred[t >> 6] = sm;
    __syncthreads();
    sm = wred[0] + wred[1] + wred[2] + wred[3];

    float al = ex / sm;
    if (t < NPIX) {
        sal[t] = al;
        out[BATCH * KDIM + b * NPIX + t] = al;
    }
    __syncthreads();

    // context: each thread owns cols 2t, 2t+1
    float c0 = 0.f, c1 = 0.f;
    const float* eb = enc + (size_t)b * NPIX * KDIM;
    const int col = 2 * t;
    for (int p = 0; p < NPIX; ++p) {
        float a = sal[p];
        float2 v = *(const float2*)(eb + (size_t)p * KDIM + col);
        c0 = fmaf(v.x, a, c0);
        c1 = fmaf(v.y, a, c1);
    }
    out[b * KDIM + col] = c0;
    out[b * KDIM + col + 1] = c1;
}

extern "C" void kernel_launch(void* const* d_in, const int* in_sizes, int n_in,
                              void* d_out, int out_size, void* d_ws, size_t ws_size,
                              hipStream_t stream) {
    const float* encoder = (const float*)d_in[0];   // [512,196,512]
    const float* dec_h   = (const float*)d_in[1];   // [512,512]
    const float* W_enc   = (const float*)d_in[2];   // [512,512]
    const float* b_enc   = (const float*)d_in[3];   // [512]
    const float* W_dec   = (const float*)d_in[4];   // [512,512]
    const float* b_dec   = (const float*)d_in[5];   // [512]
    const float* w_full  = (const float*)d_in[6];   // [512]
    float* out = (float*)d_out;                     // context [512,512] ++ alpha [512,196]

    short* wt_enc = (short*)d_ws;                   // 512*512 bf16
    short* wt_dec = wt_enc + 512 * 512;             // 512*512 bf16
    float* attdec = (float*)(wt_dec + 512 * 512);   // [512][512] fp32 (incl. both biases)
    float* energy8 = attdec + 512 * 512;            // [8][100352] fp32 partials

    // 1) weight transpose + bf16 convert
    prep_w<<<dim3(512, 2), 512, 0, stream>>>(W_enc, W_dec, wt_enc, wt_dec);

    // 2) att_dec' = dec_h @ W_dec + b_dec + b_enc   (store fp32 [512][512])
    gemm_fused<0><<<dim3(4, 4), 256, 0, stream>>>(dec_h, 512, wt_dec,
                                                  b_enc, b_dec, nullptr, nullptr, attdec);

    // 3) main fused GEMM -> energy partials
    gemm_fused<1><<<dim3(4, M_MAIN / BM), 256, 0, stream>>>(encoder, M_MAIN, wt_enc,
                                                            nullptr, nullptr, attdec, w_full, energy8);

    // 4) softmax + context
    softmax_ctx<<<dim3(BATCH), 256, 0, stream>>>(encoder, energy8, out);
}

// Round 2
// 181.742 us; speedup vs baseline: 1.1760x; 1.1760x over previous
//
#include <hip/hip_runtime.h>
#include <hip/hip_bf16.h>
#include <cstdint>

#define KDIM 512
#define BM 128
#define BN 128
#define BK 64
#define M_MAIN 100352   // 512*196
#define NPIX 196
#define BATCH 512

typedef float f32x4 __attribute__((ext_vector_type(4)));
typedef short s16x8 __attribute__((ext_vector_type(8)));
typedef short s16x4 __attribute__((ext_vector_type(4)));

__device__ __forceinline__ short f2bf(float f) {
    uint32_t u = __float_as_uint(f);
    uint32_t r = u + 0x7FFFu + ((u >> 16) & 1u);   // round-to-nearest-even
    return (short)(r >> 16);
}

__device__ __forceinline__ void gload_lds16(const void* g, void* l) {
    __builtin_amdgcn_global_load_lds(
        (const __attribute__((address_space(1))) void*)g,
        (__attribute__((address_space(3))) void*)l, 16, 0, 0);
}

// Transpose + convert W [K][A] fp32 -> Wt [A][K] bf16 for both weight matrices.
__global__ void prep_w(const float* __restrict__ W_enc, const float* __restrict__ W_dec,
                       short* __restrict__ Wt_enc, short* __restrict__ Wt_dec) {
    int a = blockIdx.x;
    int k = threadIdx.x;
    const float* W = blockIdx.y ? W_dec : W_enc;
    short* Wt = blockIdx.y ? Wt_dec : Wt_enc;
    Wt[a * KDIM + k] = f2bf(W[(size_t)k * KDIM + a]);
}

// EPI==0: write out[row][col] = acc + b1[col] + b2[col]   (att_dec' precompute)
// EPI==1: energy partials: out[(bx*2+wn)*M + row] =
//           sum_cols relu(acc + attdec[row/196][col]) * wfull[col]
// Grid is 1D; block index is XCD-swizzled then decomposed (col = swz&3, row = swz>>2).
// LDS tiles are XOR-swizzled: 16B slot s of row r holds logical slot s^(r&7)
// (T2 / st-style swizzle; B is staged via global_load_lds so its global SOURCE
// column is pre-swizzled instead of the LDS destination — rule #21).
template <int EPI>
__launch_bounds__(256, 2)
__global__ void gemm_fused(const float* __restrict__ A, int M,
                           const short* __restrict__ Bt,
                           const float* __restrict__ b1, const float* __restrict__ b2,
                           const float* __restrict__ attdec, const float* __restrict__ wfull,
                           float* __restrict__ outp) {
    __shared__ short lds_a[2][BM][BK];
    __shared__ short lds_b[2][BN][BK];

    const int tid = threadIdx.x;
    const int wave = tid >> 6;
    const int lane = tid & 63;
    const int wm = wave >> 1;       // 2 waves along M
    const int wn = wave & 1;        // 2 waves along N
    // XCD-aware bijective swizzle (gridDim.x % 8 == 0 for both instantiations)
    const int nwg = gridDim.x;
    const int q = nwg >> 3;
    const int swzb = (blockIdx.x & 7) * q + (blockIdx.x >> 3);
    const int bx = swzb & 3;        // N/BN = 4 column blocks
    const int by = swzb >> 2;
    const int r0 = by * BM;
    const int c0 = bx * BN;

    f32x4 areg[8];

    auto loadA = [&](int kt) {
#pragma unroll
        for (int j = 0; j < 8; ++j) {
            int f = tid + 256 * j;          // float4 index in 128x64 tile (16 per row)
            int row = f >> 4, c4 = f & 15;
            areg[j] = *(const f32x4*)(A + (size_t)(r0 + row) * KDIM + kt * BK + c4 * 4);
        }
    };
    auto writeA = [&](int buf) {
#pragma unroll
        for (int j = 0; j < 8; ++j) {
            int f = tid + 256 * j;
            int row = f >> 4;
            int cs = (f & 15) * 4;                    // short index in row
            int cw = cs ^ ((row & 7) * 8);            // XOR-swizzle 16B slot
            f32x4 v = areg[j];
            s16x4 o;
            o[0] = f2bf(v[0]); o[1] = f2bf(v[1]); o[2] = f2bf(v[2]); o[3] = f2bf(v[3]);
            *(s16x4*)&lds_a[buf][row][cw] = o;
        }
    };
    auto stageB = [&](int buf, int kt) {
#pragma unroll
        for (int i = 0; i < 4; ++i) {
            int rb = wave * 32 + i * 8;     // 8 rows per issue (64 lanes * 16B)
            // lane l writes LDS physical slot (row rb+(l>>3), slot l&7); pre-swizzle
            // the SOURCE column so physical slot p holds logical slot p^(row&7).
            int srcslot = (lane & 7) ^ (lane >> 3);
            const short* g = Bt + (size_t)(c0 + rb + (lane >> 3)) * KDIM + kt * BK + srcslot * 8;
            gload_lds16(g, &lds_b[buf][rb][0]);
        }
    };

    f32x4 acc[4][4];
#pragma unroll
    for (int i = 0; i < 4; ++i)
#pragma unroll
        for (int j = 0; j < 4; ++j)
            acc[i][j] = (f32x4){0.f, 0.f, 0.f, 0.f};

    auto compute = [&](int buf) {
#pragma unroll
        for (int kk = 0; kk < 2; ++kk) {
            s16x8 af[4], bf[4];
#pragma unroll
            for (int fm = 0; fm < 4; ++fm) {
                int ra = wm * 64 + fm * 16 + (lane & 15);
                af[fm] = *(const s16x8*)&lds_a[buf][ra][(kk * 32 + (lane >> 4) * 8) ^ ((ra & 7) * 8)];
            }
#pragma unroll
            for (int fn = 0; fn < 4; ++fn) {
                int rb = wn * 64 + fn * 16 + (lane & 15);
                bf[fn] = *(const s16x8*)&lds_b[buf][rb][(kk * 32 + (lane >> 4) * 8) ^ ((rb & 7) * 8)];
            }
#pragma unroll
            for (int fm = 0; fm < 4; ++fm)
#pragma unroll
                for (int fn = 0; fn < 4; ++fn)
                    acc[fm][fn] = __builtin_amdgcn_mfma_f32_16x16x32_bf16(af[fm], bf[fn], acc[fm][fn], 0, 0, 0);
        }
    };

    // Prologue: stage tile 0
    loadA(0);
    stageB(0, 0);
    writeA(0);
    __syncthreads();

    const int nk = KDIM / BK;   // 8
    for (int t = 0; t < nk; ++t) {
        int cur = t & 1;
        if (t + 1 < nk) {
            loadA(t + 1);
            stageB(cur ^ 1, t + 1);
        }
        compute(cur);
        if (t + 1 < nk) writeA(cur ^ 1);
        __syncthreads();
    }

    const int lcol = lane & 15;
    const int lrg = (lane >> 4) * 4;

    if constexpr (EPI == 0) {
#pragma unroll
        for (int fm = 0; fm < 4; ++fm)
#pragma unroll
            for (int fn = 0; fn < 4; ++fn) {
                int col = c0 + wn * 64 + fn * 16 + lcol;
                float bias = b1[col] + b2[col];
#pragma unroll
                for (int reg = 0; reg < 4; ++reg) {
                    int row = r0 + wm * 64 + fm * 16 + lrg + reg;
                    outp[(size_t)row * KDIM + col] = acc[fm][fn][reg] + bias;
                }
            }
    } else {
        float wfv[4];
        int colv[4];
#pragma unroll
        for (int fn = 0; fn < 4; ++fn) {
            colv[fn] = c0 + wn * 64 + fn * 16 + lcol;
            wfv[fn] = wfull[colv[fn]];
        }
        const int slice = bx * 2 + wn;
#pragma unroll
        for (int fm = 0; fm < 4; ++fm) {
#pragma unroll
            for (int reg = 0; reg < 4; ++reg) {
                int row = r0 + wm * 64 + fm * 16 + lrg + reg;
                int b = row / NPIX;
                float es = 0.f;
#pragma unroll
                for (int fn = 0; fn < 4; ++fn) {
                    float v = acc[fm][fn][reg] + attdec[(size_t)b * KDIM + colv[fn]];
                    v = fmaxf(v, 0.f);
                    es = fmaf(v, wfv[fn], es);
                }
#pragma unroll
                for (int m = 1; m < 16; m <<= 1) es += __shfl_xor(es, m);
                if (lcol == 0) outp[(size_t)slice * M + row] = es;
            }
        }
    }
}

// One block per batch element: sum 8 energy partials, softmax over 196, write alpha,
// then context[b][e] = sum_p enc[b][p][e] * alpha[p].
__global__ void softmax_ctx(const float* __restrict__ enc, const float* __restrict__ energy8,
                            float* __restrict__ out) {
    const int b = blockIdx.x;
    const int t = threadIdx.x;  // 256
    __shared__ float sal[NPIX];
    __shared__ float wred[4];

    float e = -1e30f;
    if (t < NPIX) {
        float s = 0.f;
#pragma unroll
        for (int i = 0; i < 8; ++i) s += energy8[(size_t)i * M_MAIN + b * NPIX + t];
        e = s;
    }
    float m = e;
#pragma unroll
    for (int d = 1; d < 64; d <<= 1) m = fmaxf(m, __shfl_xor(m, d));
    if ((t & 63) == 0) wred[t >> 6] = m;
    __syncthreads();
    m = fmaxf(fmaxf(wred[0], wred[1]), fmaxf(wred[2], wred[3]));

    float ex = (t < NPIX) ? __expf(e - m) : 0.f;
    float sm = ex;
#pragma unroll
    for (int d = 1; d < 64; d <<= 1) sm += __shfl_xor(sm, d);
    __syncthreads();
    if ((t & 63) == 0) wred[t >> 6] = sm;
    __syncthreads();
    sm = wred[0] + wred[1] + wred[2] + wred[3];

    float al = ex / sm;
    if (t < NPIX) {
        sal[t] = al;
        out[BATCH * KDIM + b * NPIX + t] = al;
    }
    __syncthreads();

    // context: each thread owns cols 2t, 2t+1
    float c0 = 0.f, c1 = 0.f;
    const float* eb = enc + (size_t)b * NPIX * KDIM;
    const int col = 2 * t;
    for (int p = 0; p < NPIX; ++p) {
        float a = sal[p];
        float2 v = *(const float2*)(eb + (size_t)p * KDIM + col);
        c0 = fmaf(v.x, a, c0);
        c1 = fmaf(v.y, a, c1);
    }
    out[b * KDIM + col] = c0;
    out[b * KDIM + col + 1] = c1;
}

extern "C" void kernel_launch(void* const* d_in, const int* in_sizes, int n_in,
                              void* d_out, int out_size, void* d_ws, size_t ws_size,
                              hipStream_t stream) {
    const float* encoder = (const float*)d_in[0];   // [512,196,512]
    const float* dec_h   = (const float*)d_in[1];   // [512,512]
    const float* W_enc   = (const float*)d_in[2];   // [512,512]
    const float* b_enc   = (const float*)d_in[3];   // [512]
    const float* W_dec   = (const float*)d_in[4];   // [512,512]
    const float* b_dec   = (const float*)d_in[5];   // [512]
    const float* w_full  = (const float*)d_in[6];   // [512]
    float* out = (float*)d_out;                     // context [512,512] ++ alpha [512,196]

    short* wt_enc = (short*)d_ws;                   // 512*512 bf16
    short* wt_dec = wt_enc + 512 * 512;             // 512*512 bf16
    float* attdec = (float*)(wt_dec + 512 * 512);   // [512][512] fp32 (incl. both biases)
    float* energy8 = attdec + 512 * 512;            // [8][100352] fp32 partials

    // 1) weight transpose + bf16 convert
    prep_w<<<dim3(512, 2), 512, 0, stream>>>(W_enc, W_dec, wt_enc, wt_dec);

    // 2) att_dec' = dec_h @ W_dec + b_dec + b_enc   (store fp32 [512][512])
    gemm_fused<0><<<dim3(16), 256, 0, stream>>>(dec_h, 512, wt_dec,
                                                b_enc, b_dec, nullptr, nullptr, attdec);

    // 3) main fused GEMM -> energy partials
    gemm_fused<1><<<dim3(4 * (M_MAIN / BM)), 256, 0, stream>>>(encoder, M_MAIN, wt_enc,
                                                               nullptr, nullptr, attdec, w_full, energy8);

    // 4) softmax + context
    softmax_ctx<<<dim3(BATCH), 256, 0, stream>>>(encoder, energy8, out);
}

// Round 3
// 150.881 us; speedup vs baseline: 1.4165x; 1.2045x over previous
//
#include <hip/hip_runtime.h>
#include <hip/hip_bf16.h>
#include <cstdint>

#define KDIM 512
#define BM 128
#define BN 128
#define BK 64
#define M_MAIN 100352   // 512*196
#define NPIX 196
#define BATCH 512

typedef float f32x4 __attribute__((ext_vector_type(4)));
typedef short s16x8 __attribute__((ext_vector_type(8)));

__device__ __forceinline__ short f2bf(float f) {
    uint32_t u = __float_as_uint(f);
    uint32_t r = u + 0x7FFFu + ((u >> 16) & 1u);   // round-to-nearest-even
    return (short)(r >> 16);
}

__device__ __forceinline__ void gload_lds16(const void* g, void* l) {
    __builtin_amdgcn_global_load_lds(
        (const __attribute__((address_space(1))) void*)g,
        (__attribute__((address_space(3))) void*)l, 16, 0, 0);
}

// Transpose + convert W [K][A] fp32 -> Wt [A][K] bf16 for both weight matrices.
__global__ void prep_w(const float* __restrict__ W_enc, const float* __restrict__ W_dec,
                       short* __restrict__ Wt_enc, short* __restrict__ Wt_dec) {
    int a = blockIdx.x;
    int k = threadIdx.x;
    const float* W = blockIdx.y ? W_dec : W_enc;
    short* Wt = blockIdx.y ? Wt_dec : Wt_enc;
    Wt[a * KDIM + k] = f2bf(W[(size_t)k * KDIM + a]);
}

// 512 threads = 8 waves as 2(M) x 4(N); per-wave output 64x32 (acc[4][2] frags).
// EPI==0: out[row][col] = acc + b1[col] + b2[col]        (att_dec' precompute)
// EPI==1: energy partial per column-block: after in-block LDS reduction over the
//         4 wn-waves, out[bx*M + row] = sum_{cols of bx} relu(acc+attdec)*wfull.
// LDS tiles XOR-swizzled: 16B slot s of row r holds logical slot s^(r&7).
// B staged via global_load_lds -> pre-swizzle the global SOURCE column (rule #21).
template <int EPI>
__launch_bounds__(512, 4)
__global__ void gemm_fused(const float* __restrict__ A, int M,
                           const short* __restrict__ Bt,
                           const float* __restrict__ b1, const float* __restrict__ b2,
                           const float* __restrict__ attdec, const float* __restrict__ wfull,
                           float* __restrict__ outp) {
    __shared__ short lds_a[2][BM][BK];
    __shared__ short lds_b[2][BN][BK];

    const int tid = threadIdx.x;
    const int wave = tid >> 6;
    const int lane = tid & 63;
    const int wm = wave >> 2;       // 2 waves along M
    const int wn = wave & 3;        // 4 waves along N
    // XCD-aware bijective swizzle (gridDim.x % 8 == 0 for both instantiations)
    const int nwg = gridDim.x;
    const int q = nwg >> 3;
    const int swzb = (blockIdx.x & 7) * q + (blockIdx.x >> 3);
    const int bx = swzb & 3;        // N/BN = 4 column blocks
    const int by = swzb >> 2;
    const int r0 = by * BM;
    const int c0 = bx * BN;

    f32x4 areg[4];

    auto loadA = [&](int kt) {
#pragma unroll
        for (int j = 0; j < 4; ++j) {
            int f = tid + 512 * j;          // float4 index in 128x64 tile (16 per row)
            int row = f >> 4, c4 = f & 15;
            areg[j] = *(const f32x4*)(A + (size_t)(r0 + row) * KDIM + kt * BK + c4 * 4);
        }
    };
    auto writeA = [&](int buf) {
#pragma unroll
        for (int j = 0; j < 4; ++j) {
            int f = tid + 512 * j;
            int row = f >> 4;
            int cs = (f & 15) * 4;                    // short index in row
            int cw = cs ^ ((row & 7) * 8);            // XOR-swizzle 16B slot
            f32x4 v = areg[j];
            __hip_bfloat162 p0 = __float22bfloat162_rn(float2{v[0], v[1]});
            __hip_bfloat162 p1 = __float22bfloat162_rn(float2{v[2], v[3]});
            uint2 w;
            w.x = *reinterpret_cast<uint32_t*>(&p0);
            w.y = *reinterpret_cast<uint32_t*>(&p1);
            *reinterpret_cast<uint2*>(&lds_a[buf][row][cw]) = w;
        }
    };
    auto stageB = [&](int buf, int kt) {
#pragma unroll
        for (int i = 0; i < 2; ++i) {
            int rb = wave * 16 + i * 8;     // 8 rows per issue (64 lanes * 16B)
            // physical slot for lane l is (row rb+(l>>3), slot l&7); pre-swizzle the
            // SOURCE column so physical slot p holds logical slot p^(row&7).
            int srcslot = (lane & 7) ^ (lane >> 3);
            const short* g = Bt + (size_t)(c0 + rb + (lane >> 3)) * KDIM + kt * BK + srcslot * 8;
            gload_lds16(g, &lds_b[buf][rb][0]);
        }
    };

    f32x4 acc[4][2];
#pragma unroll
    for (int i = 0; i < 4; ++i)
#pragma unroll
        for (int j = 0; j < 2; ++j)
            acc[i][j] = (f32x4){0.f, 0.f, 0.f, 0.f};

    auto compute = [&](int buf) {
#pragma unroll
        for (int kk = 0; kk < 2; ++kk) {
            s16x8 af[4], bf[2];
#pragma unroll
            for (int fm = 0; fm < 4; ++fm) {
                int ra = wm * 64 + fm * 16 + (lane & 15);
                af[fm] = *(const s16x8*)&lds_a[buf][ra][(kk * 32 + (lane >> 4) * 8) ^ ((ra & 7) * 8)];
            }
#pragma unroll
            for (int fn = 0; fn < 2; ++fn) {
                int rb = wn * 32 + fn * 16 + (lane & 15);
                bf[fn] = *(const s16x8*)&lds_b[buf][rb][(kk * 32 + (lane >> 4) * 8) ^ ((rb & 7) * 8)];
            }
#pragma unroll
            for (int fm = 0; fm < 4; ++fm)
#pragma unroll
                for (int fn = 0; fn < 2; ++fn)
                    acc[fm][fn] = __builtin_amdgcn_mfma_f32_16x16x32_bf16(af[fm], bf[fn], acc[fm][fn], 0, 0, 0);
        }
    };

    // Prologue: stage tile 0
    loadA(0);
    stageB(0, 0);
    writeA(0);
    __syncthreads();

    const int nk = KDIM / BK;   // 8
    for (int t = 0; t < nk; ++t) {
        int cur = t & 1;
        if (t + 1 < nk) {
            loadA(t + 1);
            stageB(cur ^ 1, t + 1);
        }
        compute(cur);
        if (t + 1 < nk) writeA(cur ^ 1);
        __syncthreads();
    }

    const int lcol = lane & 15;
    const int lrg = (lane >> 4) * 4;

    if constexpr (EPI == 0) {
#pragma unroll
        for (int fm = 0; fm < 4; ++fm)
#pragma unroll
            for (int fn = 0; fn < 2; ++fn) {
                int col = c0 + wn * 32 + fn * 16 + lcol;
                float bias = b1[col] + b2[col];
#pragma unroll
                for (int reg = 0; reg < 4; ++reg) {
                    int row = r0 + wm * 64 + fm * 16 + lrg + reg;
                    outp[(size_t)row * KDIM + col] = acc[fm][fn][reg] + bias;
                }
            }
    } else {
        float wfv[2];
        int colv[2];
#pragma unroll
        for (int fn = 0; fn < 2; ++fn) {
            colv[fn] = c0 + wn * 32 + fn * 16 + lcol;
            wfv[fn] = wfull[colv[fn]];
        }
        // per-wave partial energies -> LDS (reuse lds_a; safe after loop's final barrier)
        float* ebuf = reinterpret_cast<float*>(lds_a);   // [4 wn][128 rows]
#pragma unroll
        for (int fm = 0; fm < 4; ++fm) {
#pragma unroll
            for (int reg = 0; reg < 4; ++reg) {
                int row = r0 + wm * 64 + fm * 16 + lrg + reg;
                int b = row / NPIX;
                float es = 0.f;
#pragma unroll
                for (int fn = 0; fn < 2; ++fn) {
                    float v = acc[fm][fn][reg] + attdec[(size_t)b * KDIM + colv[fn]];
                    v = fmaxf(v, 0.f);
                    es = fmaf(v, wfv[fn], es);
                }
#pragma unroll
                for (int m = 1; m < 16; m <<= 1) es += __shfl_xor(es, m);
                if (lcol == 0) ebuf[wn * BM + wm * 64 + fm * 16 + lrg + reg] = es;
            }
        }
        __syncthreads();
        if (tid < BM) {
            float s = (ebuf[tid] + ebuf[BM + tid]) + (ebuf[2 * BM + tid] + ebuf[3 * BM + tid]);
            outp[(size_t)bx * M + r0 + tid] = s;
        }
    }
}

// One block per batch element: sum 4 energy partials, softmax over 196, write alpha,
// then context[b][e] = sum_p enc[b][p][e] * alpha[p].
__global__ void softmax_ctx(const float* __restrict__ enc, const float* __restrict__ energy4,
                            float* __restrict__ out) {
    const int b = blockIdx.x;
    const int t = threadIdx.x;  // 256
    __shared__ float sal[NPIX];
    __shared__ float wred[4];

    float e = -1e30f;
    if (t < NPIX) {
        float s = 0.f;
#pragma unroll
        for (int i = 0; i < 4; ++i) s += energy4[(size_t)i * M_MAIN + b * NPIX + t];
        e = s;
    }
    float m = e;
#pragma unroll
    for (int d = 1; d < 64; d <<= 1) m = fmaxf(m, __shfl_xor(m, d));
    if ((t & 63) == 0) wred[t >> 6] = m;
    __syncthreads();
    m = fmaxf(fmaxf(wred[0], wred[1]), fmaxf(wred[2], wred[3]));

    float ex = (t < NPIX) ? __expf(e - m) : 0.f;
    float sm = ex;
#pragma unroll
    for (int d = 1; d < 64; d <<= 1) sm += __shfl_xor(sm, d);
    __syncthreads();
    if ((t & 63) == 0) wred[t >> 6] = sm;
    __syncthreads();
    sm = wred[0] + wred[1] + wred[2] + wred[3];

    float al = ex / sm;
    if (t < NPIX) {
        sal[t] = al;
        out[BATCH * KDIM + b * NPIX + t] = al;
    }
    __syncthreads();

    // context: each thread owns cols 2t, 2t+1
    float c0 = 0.f, c1 = 0.f;
    const float* eb = enc + (size_t)b * NPIX * KDIM;
    const int col = 2 * t;
    for (int p = 0; p < NPIX; ++p) {
        float a = sal[p];
        float2 v = *(const float2*)(eb + (size_t)p * KDIM + col);
        c0 = fmaf(v.x, a, c0);
        c1 = fmaf(v.y, a, c1);
    }
    out[b * KDIM + col] = c0;
    out[b * KDIM + col + 1] = c1;
}

extern "C" void kernel_launch(void* const* d_in, const int* in_sizes, int n_in,
                              void* d_out, int out_size, void* d_ws, size_t ws_size,
                              hipStream_t stream) {
    const float* encoder = (const float*)d_in[0];   // [512,196,512]
    const float* dec_h   = (const float*)d_in[1];   // [512,512]
    const float* W_enc   = (const float*)d_in[2];   // [512,512]
    const float* b_enc   = (const float*)d_in[3];   // [512]
    const float* W_dec   = (const float*)d_in[4];   // [512,512]
    const float* b_dec   = (const float*)d_in[5];   // [512]
    const float* w_full  = (const float*)d_in[6];   // [512]
    float* out = (float*)d_out;                     // context [512,512] ++ alpha [512,196]

    short* wt_enc = (short*)d_ws;                   // 512*512 bf16
    short* wt_dec = wt_enc + 512 * 512;             // 512*512 bf16
    float* attdec = (float*)(wt_dec + 512 * 512);   // [512][512] fp32 (incl. both biases)
    float* energy4 = attdec + 512 * 512;            // [4][100352] fp32 partials

    // 1) weight transpose + bf16 convert
    prep_w<<<dim3(512, 2), 512, 0, stream>>>(W_enc, W_dec, wt_enc, wt_dec);

    // 2) att_dec' = dec_h @ W_dec + b_dec + b_enc   (store fp32 [512][512])
    gemm_fused<0><<<dim3(16), 512, 0, stream>>>(dec_h, 512, wt_dec,
                                                b_enc, b_dec, nullptr, nullptr, attdec);

    // 3) main fused GEMM -> energy partials (4 column-block slices)
    gemm_fused<1><<<dim3(4 * (M_MAIN / BM)), 512, 0, stream>>>(encoder, M_MAIN, wt_enc,
                                                               nullptr, nullptr, attdec, w_full, energy4);

    // 4) softmax + context
    softmax_ctx<<<dim3(BATCH), 256, 0, stream>>>(encoder, energy4, out);
}